// Round 10
// baseline (61.689 us; speedup 1.0000x reference)
//
#include <hip/hip_runtime.h>
#include <hip/hip_bf16.h>

typedef __attribute__((ext_vector_type(8))) short short8;
typedef __attribute__((ext_vector_type(4))) float f32x4;
typedef __attribute__((ext_vector_type(2))) long long2t;

__device__ __forceinline__ short f2bf(float x) {
  union { float f; unsigned u; } a; a.f = x;
  unsigned r = (a.u + 0x7FFFu + ((a.u >> 16) & 1u)) >> 16;
  return (short)r;
}
__device__ __forceinline__ float bf2f(short x) {
  union { unsigned u; float f; } a; a.u = ((unsigned)(unsigned short)x) << 16;
  return a.f;
}
__device__ __forceinline__ unsigned cvtpk(float lo, float hi) {
  unsigned r;
  asm("v_cvt_pk_bf16_f32 %0, %1, %2" : "=v"(r) : "v"(lo), "v"(hi));
  return r;
}
// pack 4 floats -> 4 fp8(e4m3) bytes
__device__ __forceinline__ unsigned pk8(float a, float b, float c, float d) {
  unsigned lo, hi;
  asm("v_cvt_pk_fp8_f32 %0, %1, %2" : "=v"(lo) : "v"(a), "v"(b));
  asm("v_cvt_pk_fp8_f32 %0, %1, %2" : "=v"(hi) : "v"(c), "v"(d));
  return (lo & 0xffffu) | (hi << 16);
}
__device__ __forceinline__ long2t as_l2(uint4 v) {
  union { uint4 u; long2t l; } cc; cc.u = v; return cc.l;
}
__device__ __forceinline__ void gload16(const void* g, void* l) {
  __builtin_amdgcn_global_load_lds((const __attribute__((address_space(1))) unsigned int*)g,
                                   (__attribute__((address_space(3))) unsigned int*)l, 16, 0, 0);
}

#define QSC 0.18033688011112042f  // log2(e)/8

// ---------------- K0: combined-weight precompute + situation path ----------------
// Wcomb rows: 0-63 = Wt ; 64-127 = QSC*Wsaq@Wt ; 128-191 = Wsak@Wt ; 192-255 = Wsav@Wt  (bf16)
// wcol4/bias4: matching last-column (bil coefficient) and combined bias, f32.
__global__ __launch_bounds__(256) void ca_comb(
    const float* __restrict__ Wt, const float* __restrict__ bt,
    const float* __restrict__ Wsaq, const float* __restrict__ bsaq,
    const float* __restrict__ Wsak, const float* __restrict__ bsak,
    const float* __restrict__ Wsav, const float* __restrict__ bsav,
    short* __restrict__ Wcomb, float* __restrict__ wcol4, float* __restrict__ bias4,
    const float* __restrict__ sit, const float* __restrict__ Ws, const float* __restrict__ bs,
    const float* __restrict__ Wck, const float* __restrict__ bck,
    const float* __restrict__ Wcv, const float* __restrict__ bcv,
    const float* __restrict__ Wcq, const float* __restrict__ bcq,
    const float* __restrict__ Wsc, float* __restrict__ u_ws, float* __restrict__ scal) {
  const int bid = blockIdx.x, t = threadIdx.x;
  if (bid < 96) {
    __shared__ float Wtc[64][4];
    const int c0 = bid * 4;
    { int j = t & 63, cc = t >> 6; Wtc[j][cc] = Wt[(size_t)j * 385 + c0 + cc]; }
    __syncthreads();
    const int r = t;
    float o[4] = {0.f, 0.f, 0.f, 0.f};
    if (r < 64) {
#pragma unroll
      for (int cc = 0; cc < 4; ++cc) o[cc] = Wtc[r][cc];
    } else {
      const int m = (r >> 6) - 1, rr = r & 63;
      const float* Wm = (m == 0 ? Wsaq : m == 1 ? Wsak : Wsav) + (size_t)rr * 64;
      for (int j = 0; j < 64; ++j) {
        float wv = Wm[j];
#pragma unroll
        for (int cc = 0; cc < 4; ++cc) o[cc] += wv * Wtc[j][cc];
      }
      if (m == 0) {
#pragma unroll
        for (int cc = 0; cc < 4; ++cc) o[cc] *= QSC;
      }
    }
#pragma unroll
    for (int cc = 0; cc < 4; ++cc) Wcomb[(size_t)r * 384 + c0 + cc] = f2bf(o[cc]);
    return;
  }
  // ---- block 96: situation path + wcol4/bias4 ----
  __shared__ float part[4][64];
  __shared__ float sh[64], ck[64], cv[64];
  {
    int j = t & 63, p = t >> 6;
    float a = 0.f;
    for (int d = p * 96; d < p * 96 + 96; ++d) a += Ws[j * 384 + d] * sit[d];
    part[p][j] = a;
    __syncthreads();
    if (t < 64) sh[t] = part[0][t] + part[1][t] + part[2][t] + part[3][t] + bs[t];
    __syncthreads();
    if (t < 64) {
      float kk = bck[t], vv = bcv[t];
      for (int d = 0; d < 64; ++d) { kk += Wck[t * 64 + d] * sh[d]; vv += Wcv[t * 64 + d] * sh[d]; }
      ck[t] = kk; cv[t] = vv;
    }
    __syncthreads();
    if (t < 64) {
      float uu = 0.f;
      for (int jj = 0; jj < 64; ++jj) uu += Wcq[jj * 64 + t] * ck[jj];
      u_ws[t] = uu;
    }
    if (t == 0) {
      float c0s = 0.f, cw = 0.f;
      for (int jj = 0; jj < 64; ++jj) { c0s += bcq[jj] * ck[jj]; cw += cv[jj] * Wsc[jj]; }
      scal[0] = c0s; scal[1] = cw;
    }
  }
  // wcol4 / bias4
  {
    const int r = t;
    float wc, bb;
    if (r < 64) {
      wc = Wt[(size_t)r * 385 + 384];
      bb = bt[r];
    } else {
      const int m = (r >> 6) - 1, rr = r & 63;
      const float* Wm = (m == 0 ? Wsaq : m == 1 ? Wsak : Wsav) + (size_t)rr * 64;
      const float* bm = (m == 0 ? bsaq : m == 1 ? bsak : bsav);
      float s1 = 0.f, s2 = 0.f;
      for (int j = 0; j < 64; ++j) {
        float wv = Wm[j];
        s1 += wv * Wt[(size_t)j * 385 + 384];
        s2 += wv * bt[j];
      }
      float sc = (m == 0) ? QSC : 1.f;
      wc = sc * s1;
      bb = sc * (s2 + bm[rr]);
    }
    wcol4[r] = wc;
    bias4[r] = bb;
  }
}

// ---------------- K1: single-phase projection GEMM from te (wave w -> matrix w) ----------------
// grid N/32 blocks x 256 thr. Wave 0 -> hb (bf16), 1 -> qb8, 2 -> kb8, 3 -> vl8 (fp8 frag layouts).
__global__ __launch_bounds__(256) void ca_proj5(
    const float* __restrict__ te, const float* __restrict__ bil,
    const short* __restrict__ Wcomb, const float* __restrict__ wcol4,
    const float* __restrict__ bias4,
    short* __restrict__ hb, unsigned char* __restrict__ qb8,
    unsigned char* __restrict__ kb8, unsigned char* __restrict__ vl8, int N) {
  __shared__ short Hl[32][72];
  __shared__ unsigned char Q8[32][72];
  __shared__ unsigned char K8[32][72];
  __shared__ unsigned char V8s[64][32];
  const int t = threadIdx.x, lane = t & 63, w = t >> 6;
  const int g = lane >> 4, li = lane & 15;
  const int i0 = blockIdx.x * 32;

  f32x4 acc[2][4];
#pragma unroll
  for (int qs = 0; qs < 2; ++qs)
#pragma unroll
    for (int n = 0; n < 4; ++n) acc[qs][n] = (f32x4){0.f, 0.f, 0.f, 0.f};

#pragma unroll 4
  for (int ks = 0; ks < 12; ++ks) {
    short8 af[2];
#pragma unroll
    for (int qs = 0; qs < 2; ++qs) {
      const float* ap = te + (size_t)(i0 + qs * 16 + li) * 384 + ks * 32 + g * 8;
      float4 a0 = *(const float4*)ap;
      float4 a1 = *(const float4*)(ap + 4);
      af[qs][0] = f2bf(a0.x); af[qs][1] = f2bf(a0.y); af[qs][2] = f2bf(a0.z); af[qs][3] = f2bf(a0.w);
      af[qs][4] = f2bf(a1.x); af[qs][5] = f2bf(a1.y); af[qs][6] = f2bf(a1.z); af[qs][7] = f2bf(a1.w);
    }
#pragma unroll
    for (int n = 0; n < 4; ++n) {
      short8 bf = *(const short8*)&Wcomb[(size_t)(w * 64 + n * 16 + li) * 384 + ks * 32 + g * 8];
      acc[0][n] = __builtin_amdgcn_mfma_f32_16x16x32_bf16(af[0], bf, acc[0][n], 0, 0, 0);
      acc[1][n] = __builtin_amdgcn_mfma_f32_16x16x32_bf16(af[1], bf, acc[1][n], 0, 0, 0);
    }
  }

  float bilv[2][4];
#pragma unroll
  for (int qs = 0; qs < 2; ++qs)
#pragma unroll
    for (int r = 0; r < 4; ++r) bilv[qs][r] = bil[i0 + qs * 16 + g * 4 + r];
  float bb[4], wc[4];
#pragma unroll
  for (int n = 0; n < 4; ++n) {
    bb[n] = bias4[w * 64 + n * 16 + li];
    wc[n] = wcol4[w * 64 + n * 16 + li];
  }

  if (w == 0) {
#pragma unroll
    for (int qs = 0; qs < 2; ++qs)
#pragma unroll
      for (int n = 0; n < 4; ++n)
#pragma unroll
        for (int r = 0; r < 4; ++r)
          Hl[qs * 16 + g * 4 + r][n * 16 + li] =
              f2bf(acc[qs][n][r] + bb[n] + bilv[qs][r] * wc[n]);
    asm volatile("s_waitcnt lgkmcnt(0)" ::: "memory");
    __builtin_amdgcn_sched_barrier(0);
    const int row = lane >> 1, sb = (lane & 1) * 4;
#pragma unroll
    for (int k = 0; k < 4; ++k)
      *(uint4*)&hb[(size_t)(i0 + row) * 64 + (sb + k) * 8] = *(const uint4*)&Hl[row][(sb + k) * 8];
  } else if (w == 1) {
#pragma unroll
    for (int qs = 0; qs < 2; ++qs)
#pragma unroll
      for (int n = 0; n < 4; ++n) {
        unsigned u = pk8(acc[qs][n][0] + bb[n] + bilv[qs][0] * wc[n],
                         acc[qs][n][1] + bb[n] + bilv[qs][1] * wc[n],
                         acc[qs][n][2] + bb[n] + bilv[qs][2] * wc[n],
                         acc[qs][n][3] + bb[n] + bilv[qs][3] * wc[n]);
#pragma unroll
        for (int r = 0; r < 4; ++r)
          Q8[qs * 16 + g * 4 + r][n * 16 + li] = (unsigned char)(u >> (8 * r));
      }
    asm volatile("s_waitcnt lgkmcnt(0)" ::: "memory");
    __builtin_amdgcn_sched_barrier(0);
#pragma unroll
    for (int qs = 0; qs < 2; ++qs) {
      unsigned long long lo = *(const unsigned long long*)&Q8[qs * 16 + li][g * 8];
      unsigned long long hi = *(const unsigned long long*)&Q8[qs * 16 + li][32 + g * 8];
      unsigned char* dst = qb8 + (size_t)((i0 >> 4) + qs) * 1024 + lane * 16;
      *(unsigned long long*)dst = lo;
      *(unsigned long long*)(dst + 8) = hi;
    }
  } else if (w == 2) {
#pragma unroll
    for (int qs = 0; qs < 2; ++qs)
#pragma unroll
      for (int n = 0; n < 4; ++n) {
        unsigned u = pk8(acc[qs][n][0] + bb[n] + bilv[qs][0] * wc[n],
                         acc[qs][n][1] + bb[n] + bilv[qs][1] * wc[n],
                         acc[qs][n][2] + bb[n] + bilv[qs][2] * wc[n],
                         acc[qs][n][3] + bb[n] + bilv[qs][3] * wc[n]);
#pragma unroll
        for (int r = 0; r < 4; ++r)
          K8[qs * 16 + g * 4 + r][n * 16 + li] = (unsigned char)(u >> (8 * r));
      }
    asm volatile("s_waitcnt lgkmcnt(0)" ::: "memory");
    __builtin_amdgcn_sched_barrier(0);
#pragma unroll
    for (int qs = 0; qs < 2; ++qs) {
      unsigned long long lo = *(const unsigned long long*)&K8[qs * 16 + li][g * 8];
      unsigned long long hi = *(const unsigned long long*)&K8[qs * 16 + li][32 + g * 8];
      unsigned char* dst = kb8 + (size_t)((i0 >> 6) * 4 + ((i0 >> 4) & 3) + qs) * 1024 + lane * 16;
      *(unsigned long long*)dst = lo;
      *(unsigned long long*)(dst + 8) = hi;
    }
  } else {
#pragma unroll
    for (int qs = 0; qs < 2; ++qs)
#pragma unroll
      for (int n = 0; n < 4; ++n) {
        unsigned u = pk8(acc[qs][n][0] + bb[n] + bilv[qs][0] * wc[n],
                         acc[qs][n][1] + bb[n] + bilv[qs][1] * wc[n],
                         acc[qs][n][2] + bb[n] + bilv[qs][2] * wc[n],
                         acc[qs][n][3] + bb[n] + bilv[qs][3] * wc[n]);
        *(unsigned*)&V8s[n * 16 + li][qs * 16 + g * 4] = u;
      }
    asm volatile("s_waitcnt lgkmcnt(0)" ::: "memory");
    __builtin_amdgcn_sched_barrier(0);
#pragma unroll
    for (int dt = 0; dt < 4; ++dt) {
      unsigned long long v = *(const unsigned long long*)&V8s[dt * 16 + li][g * 8];
      *(unsigned long long*)(vl8 + (size_t)((i0 >> 6) * 4 + dt) * 1024 + lane * 16 +
                             ((i0 >> 5) & 1) * 8) = v;
    }
  }
}

// ---------------- K2: fp8 LDS-staged attention, swapped QK^T, 8-way key split ----------------
__global__ __launch_bounds__(128, 2) void ca_attn7(
    const uint4* __restrict__ qb8, const unsigned* __restrict__ kb8,
    const unsigned* __restrict__ vl8,
    unsigned* __restrict__ pOu, float* __restrict__ pL, int N) {
  __shared__ unsigned Kl[2][1024];
  __shared__ unsigned Vl[2][1024];
  __shared__ unsigned Pl[2][2][256];
  const int t = threadIdx.x, lane = t & 63, wid = t >> 6;
  const int g = lane >> 4, li = lane & 15;
  const int bid = blockIdx.x;
  const int sp = bid & 7, qblk = bid >> 3;
  const int i0 = qblk * 64 + wid * 32;
  const int ntil = N >> 9;
  const int tile0 = sp * ntil;

#define STG(b, T)                                                                                  \
  do {                                                                                             \
    gload16(kb8 + (((size_t)(T) * 4 + 2 * wid) << 8) + lane * 4,     &Kl[b][(2 * wid) * 256]);     \
    gload16(kb8 + (((size_t)(T) * 4 + 2 * wid + 1) << 8) + lane * 4, &Kl[b][(2 * wid + 1) * 256]); \
    gload16(vl8 + (((size_t)(T) * 4 + 2 * wid) << 8) + lane * 4,     &Vl[b][(2 * wid) * 256]);     \
    gload16(vl8 + (((size_t)(T) * 4 + 2 * wid + 1) << 8) + lane * 4, &Vl[b][(2 * wid + 1) * 256]); \
  } while (0)

  long2t qf[2];
  qf[0] = as_l2(qb8[(size_t)((i0 >> 4) + 0) * 64 + lane]);
  qf[1] = as_l2(qb8[(size_t)((i0 >> 4) + 1) * 64 + lane]);

  f32x4 acc[2][4];
  float rs[2] = {0.f, 0.f};
#pragma unroll
  for (int qs = 0; qs < 2; ++qs)
#pragma unroll
    for (int n = 0; n < 4; ++n) acc[qs][n] = (f32x4){0.f, 0.f, 0.f, 0.f};

  STG(0, tile0);
  asm volatile("s_waitcnt vmcnt(0)" ::: "memory");

  for (int tt = 0; tt < ntil; ++tt) {
    const int cur = tt & 1;
    __builtin_amdgcn_s_barrier();
    if (tt + 1 < ntil) STG(cur ^ 1, tile0 + tt + 1);

    f32x4 s4[2][4];
#pragma unroll
    for (int qs = 0; qs < 2; ++qs)
#pragma unroll
      for (int t4 = 0; t4 < 4; ++t4) s4[qs][t4] = (f32x4){0.f, 0.f, 0.f, 0.f};
    __builtin_amdgcn_s_setprio(1);
#pragma unroll
    for (int t4 = 0; t4 < 4; ++t4) {
      long2t kl = as_l2(*(const uint4*)&Kl[cur][t4 * 256 + lane * 4]);
      s4[0][t4] = __builtin_amdgcn_mfma_f32_16x16x32_fp8_fp8(kl.x, qf[0].x, s4[0][t4], 0, 0, 0);
      s4[0][t4] = __builtin_amdgcn_mfma_f32_16x16x32_fp8_fp8(kl.y, qf[0].y, s4[0][t4], 0, 0, 0);
      s4[1][t4] = __builtin_amdgcn_mfma_f32_16x16x32_fp8_fp8(kl.x, qf[1].x, s4[1][t4], 0, 0, 0);
      s4[1][t4] = __builtin_amdgcn_mfma_f32_16x16x32_fp8_fp8(kl.y, qf[1].y, s4[1][t4], 0, 0, 0);
    }
    __builtin_amdgcn_s_setprio(0);
#pragma unroll
    for (int qs = 0; qs < 2; ++qs) {
#pragma unroll
      for (int t4 = 0; t4 < 4; ++t4) {
        float p0, p1, p2, p3;
        asm("v_exp_f32 %0, %1" : "=v"(p0) : "v"(s4[qs][t4][0]));
        asm("v_exp_f32 %0, %1" : "=v"(p1) : "v"(s4[qs][t4][1]));
        asm("v_exp_f32 %0, %1" : "=v"(p2) : "v"(s4[qs][t4][2]));
        asm("v_exp_f32 %0, %1" : "=v"(p3) : "v"(s4[qs][t4][3]));
        rs[qs] += (p0 + p1) + (p2 + p3);
        unsigned u = pk8(p0, p1, p2, p3);
        Pl[wid][qs][(li + 16 * ((t4 & 1) * 2 + (g >> 1))) * 4 + (t4 >> 1) * 2 + (g & 1)] = u;
      }
    }
    asm volatile("s_waitcnt lgkmcnt(0)" ::: "memory");
    long2t pf0 = as_l2(*(const uint4*)&Pl[wid][0][lane * 4]);
    long2t pf1 = as_l2(*(const uint4*)&Pl[wid][1][lane * 4]);
    __builtin_amdgcn_s_setprio(1);
#pragma unroll
    for (int dt = 0; dt < 4; ++dt) {
      long2t vf = as_l2(*(const uint4*)&Vl[cur][dt * 256 + lane * 4]);
      acc[0][dt] = __builtin_amdgcn_mfma_f32_16x16x32_fp8_fp8(pf0.x, vf.x, acc[0][dt], 0, 0, 0);
      acc[0][dt] = __builtin_amdgcn_mfma_f32_16x16x32_fp8_fp8(pf0.y, vf.y, acc[0][dt], 0, 0, 0);
      acc[1][dt] = __builtin_amdgcn_mfma_f32_16x16x32_fp8_fp8(pf1.x, vf.x, acc[1][dt], 0, 0, 0);
      acc[1][dt] = __builtin_amdgcn_mfma_f32_16x16x32_fp8_fp8(pf1.y, vf.y, acc[1][dt], 0, 0, 0);
    }
    __builtin_amdgcn_s_setprio(0);
    asm volatile("s_waitcnt vmcnt(0)" ::: "memory");
  }
#undef STG

  const size_t ob = ((size_t)sp * (N >> 5) + (i0 >> 5)) * 2;
#pragma unroll
  for (int qs = 0; qs < 2; ++qs) {
#pragma unroll
    for (int dt = 0; dt < 4; ++dt) {
      uint2 wv;
      wv.x = cvtpk(acc[qs][dt][0], acc[qs][dt][1]);
      wv.y = cvtpk(acc[qs][dt][2], acc[qs][dt][3]);
      *(uint2*)&pOu[((ob + qs) * 4 + dt) * 128 + lane * 2] = wv;
    }
    float r2 = rs[qs] + __shfl_xor(rs[qs], 16, 64);
    r2 += __shfl_xor(r2, 32, 64);
    if (lane < 16) pL[(size_t)sp * N + i0 + qs * 16 + lane] = r2;
  }
}

// ---------------- K3: merge 8 splits (fragment layout) + residual + cross-attn + epilogue ------
__global__ __launch_bounds__(256) void ca_merge3(
    const short* __restrict__ hb, const unsigned* __restrict__ pOu, const float* __restrict__ pL,
    const float* __restrict__ u_ws, const float* __restrict__ scal,
    const float* __restrict__ bil, const float* __restrict__ Wsc,
    const float* __restrict__ bsc_p, const float* __restrict__ rgate_p,
    float* __restrict__ out, int N) {
  const int t = threadIdx.x;
  const int rp = t >> 3, e = t & 7;
  const int dt2 = e >> 1, li0 = (e & 1) * 8;
  const float gate = 1.f / (1.f + __expf(-rgate_p[0]));
  const float bsc = bsc_p[0], sc0 = scal[0], sc1 = scal[1];
  const int R0 = blockIdx.x * 64 + rp * 2;
  const int b32 = R0 >> 5, qs2 = (R0 >> 4) & 1, g2 = (R0 >> 2) & 3;
  const int rpair = (R0 & 3) >> 1;
  float o0[8], o1[8], L0 = 0.f, L1 = 0.f;
#pragma unroll
  for (int j = 0; j < 8; ++j) { o0[j] = 0.f; o1[j] = 0.f; }
#pragma unroll
  for (int sp2 = 0; sp2 < 8; ++sp2) {
    size_t base = ((((size_t)sp2 * (N >> 5) + b32) * 2 + qs2) * 4 + dt2) * 128
                  + (g2 * 16 + li0) * 2 + rpair;
#pragma unroll
    for (int j = 0; j < 8; ++j) {
      unsigned u = pOu[base + 2 * j];
      o0[j] += bf2f((short)(u & 0xffff));
      o1[j] += bf2f((short)(u >> 16));
    }
    L0 += pL[(size_t)sp2 * N + R0];
    L1 += pL[(size_t)sp2 * N + R0 + 1];
  }
  const float iL0 = 1.f / L0, iL1 = 1.f / L1;
  const int c0 = dt2 * 16 + li0;
  short8 hv0 = *(const short8*)&hb[(size_t)R0 * 64 + c0];
  short8 hv1 = *(const short8*)&hb[(size_t)(R0 + 1) * 64 + c0];
  float s1a = 0.f, s2a = 0.f, s1b = 0.f, s2b = 0.f;
#pragma unroll
  for (int j = 0; j < 8; ++j) {
    float uwsj = u_ws[c0 + j], wscj = Wsc[c0 + j];
    float h0 = bf2f(hv0[j]) + o0[j] * iL0;
    float h1 = bf2f(hv1[j]) + o1[j] * iL1;
    s1a += h0 * uwsj; s2a += h0 * wscj;
    s1b += h1 * uwsj; s2b += h1 * wscj;
  }
#pragma unroll
  for (int mask = 1; mask < 8; mask <<= 1) {
    s1a += __shfl_xor(s1a, mask, 64);
    s2a += __shfl_xor(s2a, mask, 64);
    s1b += __shfl_xor(s1b, mask, 64);
    s2b += __shfl_xor(s2b, mask, 64);
  }
  if (e == 0) {
    float cawa = 1.f / (1.f + __expf(-(s1a + sc0) * 0.125f));
    float cawb = 1.f / (1.f + __expf(-(s1b + sc0) * 0.125f));
    float scoreA = s2a + cawa * sc1 + bsc;
    float scoreB = s2b + cawb * sc1 + bsc;
    out[R0] = (1.f - gate) * bil[R0] + gate * scoreA;
    out[R0 + 1] = (1.f - gate) * bil[R0 + 1] + gate * scoreB;
  }
}

extern "C" void kernel_launch(void* const* d_in, const int* in_sizes, int n_in,
                              void* d_out, int out_size, void* d_ws, size_t ws_size,
                              hipStream_t stream) {
  const float* sit  = (const float*)d_in[0];
  const float* te   = (const float*)d_in[1];
  const float* bil  = (const float*)d_in[2];
  const float* Wt   = (const float*)d_in[3];
  const float* bt   = (const float*)d_in[4];
  const float* Ws   = (const float*)d_in[5];
  const float* bs   = (const float*)d_in[6];
  const float* Wsaq = (const float*)d_in[7];
  const float* bsaq = (const float*)d_in[8];
  const float* Wsak = (const float*)d_in[9];
  const float* bsak = (const float*)d_in[10];
  const float* Wsav = (const float*)d_in[11];
  const float* bsav = (const float*)d_in[12];
  const float* Wcq  = (const float*)d_in[13];
  const float* bcq  = (const float*)d_in[14];
  const float* Wck  = (const float*)d_in[15];
  const float* bck  = (const float*)d_in[16];
  const float* Wcv  = (const float*)d_in[17];
  const float* bcv  = (const float*)d_in[18];
  const float* Wsc  = (const float*)d_in[19];
  const float* bsc  = (const float*)d_in[20];
  const float* rgate= (const float*)d_in[21];
  const int N = in_sizes[2];

  char* w = (char*)d_ws;
  size_t off = 0;
  short* hbuf        = (short*)(w + off);         off += (size_t)N * 64 * 2;
  unsigned char* qb8 = (unsigned char*)(w + off); off += (size_t)N * 64;
  unsigned char* kb8 = (unsigned char*)(w + off); off += (size_t)N * 64;
  unsigned char* vl8 = (unsigned char*)(w + off); off += (size_t)N * 64;
  float* u_ws        = (float*)(w + off);         off += 64 * 4;
  float* scal        = (float*)(w + off);         off += 4 * 4;
  short* Wcomb       = (short*)(w + off);         off += (size_t)256 * 384 * 2;
  float* wcol4       = (float*)(w + off);         off += 256 * 4;
  float* bias4       = (float*)(w + off);         off += 256 * 4;
  unsigned* pOu      = (unsigned*)(w + off);      off += (size_t)8 * N * 64 * 2;
  float* pL          = (float*)(w + off);         off += (size_t)8 * N * 4;

  ca_comb<<<97, 256, 0, stream>>>(Wt, bt, Wsaq, bsaq, Wsak, bsak, Wsav, bsav,
                                  Wcomb, wcol4, bias4,
                                  sit, Ws, bs, Wck, bck, Wcv, bcv, Wcq, bcq, Wsc, u_ws, scal);
  ca_proj5<<<N / 32, 256, 0, stream>>>(te, bil, Wcomb, wcol4, bias4,
                                       hbuf, qb8, kb8, vl8, N);
  ca_attn7<<<N / 8, 128, 0, stream>>>((const uint4*)qb8, (const unsigned*)kb8,
                                      (const unsigned*)vl8, pOu, pL, N);
  ca_merge3<<<N / 64, 256, 0, stream>>>(hbuf, pOu, pL, u_ws, scal, bil, Wsc, bsc, rgate,
                                        (float*)d_out, N);
}

// Round 11
// 50.188 us; speedup vs baseline: 1.2292x; 1.2292x over previous
//
#include <hip/hip_runtime.h>
#include <hip/hip_bf16.h>

typedef __attribute__((ext_vector_type(8))) short short8;
typedef __attribute__((ext_vector_type(4))) float f32x4;
typedef __attribute__((ext_vector_type(2))) long long2t;

__device__ __forceinline__ short f2bf(float x) {
  union { float f; unsigned u; } a; a.f = x;
  unsigned r = (a.u + 0x7FFFu + ((a.u >> 16) & 1u)) >> 16;
  return (short)r;
}
__device__ __forceinline__ float bf2f(short x) {
  union { unsigned u; float f; } a; a.u = ((unsigned)(unsigned short)x) << 16;
  return a.f;
}
__device__ __forceinline__ unsigned cvtpk(float lo, float hi) {
  unsigned r;
  asm("v_cvt_pk_bf16_f32 %0, %1, %2" : "=v"(r) : "v"(lo), "v"(hi));
  return r;
}
// pack 4 floats -> 4 fp8(e4m3) bytes
__device__ __forceinline__ unsigned pk8(float a, float b, float c, float d) {
  unsigned lo, hi;
  asm("v_cvt_pk_fp8_f32 %0, %1, %2" : "=v"(lo) : "v"(a), "v"(b));
  asm("v_cvt_pk_fp8_f32 %0, %1, %2" : "=v"(hi) : "v"(c), "v"(d));
  return (lo & 0xffffu) | (hi << 16);
}
__device__ __forceinline__ long2t as_l2(uint4 v) {
  union { uint4 u; long2t l; } cc; cc.u = v; return cc.l;
}
__device__ __forceinline__ void gload16(const void* g, void* l) {
  __builtin_amdgcn_global_load_lds((const __attribute__((address_space(1))) unsigned int*)g,
                                   (__attribute__((address_space(3))) unsigned int*)l, 16, 0, 0);
}

// ---------------- K1: fused projections (fp8 q/k/v emission) + (last block) situation path ------
__global__ __launch_bounds__(256) void ca_proj4(
    const float* __restrict__ te, const float* __restrict__ bil,
    const float* __restrict__ Wt, const float* __restrict__ bt,
    const float* __restrict__ Wsaq, const float* __restrict__ bq,
    const float* __restrict__ Wsak, const float* __restrict__ bk2,
    const float* __restrict__ Wsav, const float* __restrict__ bv,
    short* __restrict__ hb, unsigned char* __restrict__ qb8,
    unsigned char* __restrict__ kb8, unsigned char* __restrict__ vl8,
    const float* __restrict__ sit, const float* __restrict__ Ws, const float* __restrict__ bs,
    const float* __restrict__ Wck, const float* __restrict__ bck,
    const float* __restrict__ Wcv, const float* __restrict__ bcv,
    const float* __restrict__ Wcq, const float* __restrict__ bcq,
    const float* __restrict__ Wsc, float* __restrict__ u_ws, float* __restrict__ scal,
    int N) {
  __shared__ float Pp[8192];
  __shared__ short Hl[32][72];
  __shared__ unsigned char Q8[32][72];
  __shared__ unsigned char K8[32][72];
  __shared__ unsigned char V8s[64][32];   // [d][key-local]
  __shared__ float part[4][64];
  __shared__ float sh[64], ck[64], cv[64];
  const int t = threadIdx.x;
  if ((int)blockIdx.x == (N >> 5)) {
    int j = t & 63, p = t >> 6;
    float a = 0.f;
    for (int d = p * 96; d < p * 96 + 96; ++d) a += Ws[j * 384 + d] * sit[d];
    part[p][j] = a;
    __syncthreads();
    if (t < 64) sh[t] = part[0][t] + part[1][t] + part[2][t] + part[3][t] + bs[t];
    __syncthreads();
    if (t < 64) {
      float kk = bck[t], vv = bcv[t];
      for (int d = 0; d < 64; ++d) { kk += Wck[t * 64 + d] * sh[d]; vv += Wcv[t * 64 + d] * sh[d]; }
      ck[t] = kk; cv[t] = vv;
    }
    __syncthreads();
    if (t < 64) {
      float uu = 0.f;
      for (int jj = 0; jj < 64; ++jj) uu += Wcq[jj * 64 + t] * ck[jj];
      u_ws[t] = uu;
    }
    if (t == 0) {
      float c0 = 0.f, cw = 0.f;
      for (int jj = 0; jj < 64; ++jj) { c0 += bcq[jj] * ck[jj]; cw += cv[jj] * Wsc[jj]; }
      scal[0] = c0; scal[1] = cw;
    }
    return;
  }
  const int lane = t & 63, w = t >> 6;
  const int g = lane >> 4, li = lane & 15;
  const int i0 = blockIdx.x * 32;

  // ---- phase A: partial hidden GEMM over this wave's k-range ----
  f32x4 acc[2][4];
#pragma unroll
  for (int qs = 0; qs < 2; ++qs)
#pragma unroll
    for (int n = 0; n < 4; ++n) acc[qs][n] = (f32x4){0.f, 0.f, 0.f, 0.f};
  const int kw = w * 96;
#pragma unroll
  for (int ks = 0; ks < 3; ++ks) {
    short8 af[2];
#pragma unroll
    for (int qs = 0; qs < 2; ++qs) {
      const float* ap = te + (size_t)(i0 + qs * 16 + li) * 384 + kw + ks * 32 + g * 8;
      float4 a0 = *(const float4*)ap;
      float4 a1 = *(const float4*)(ap + 4);
      af[qs][0] = f2bf(a0.x); af[qs][1] = f2bf(a0.y); af[qs][2] = f2bf(a0.z); af[qs][3] = f2bf(a0.w);
      af[qs][4] = f2bf(a1.x); af[qs][5] = f2bf(a1.y); af[qs][6] = f2bf(a1.z); af[qs][7] = f2bf(a1.w);
    }
#pragma unroll
    for (int n = 0; n < 4; ++n) {
      short8 bf;
      const float* wp = Wt + (size_t)(n * 16 + li) * 385 + kw + ks * 32 + g * 8;
#pragma unroll
      for (int jj = 0; jj < 8; ++jj) bf[jj] = f2bf(wp[jj]);
      acc[0][n] = __builtin_amdgcn_mfma_f32_16x16x32_bf16(af[0], bf, acc[0][n], 0, 0, 0);
      acc[1][n] = __builtin_amdgcn_mfma_f32_16x16x32_bf16(af[1], bf, acc[1][n], 0, 0, 0);
    }
  }
#pragma unroll
  for (int qs = 0; qs < 2; ++qs)
#pragma unroll
    for (int n = 0; n < 4; ++n)
      *(f32x4*)&Pp[((w * 8 + qs * 4 + n) * 64 + lane) * 4] = acc[qs][n];
  __syncthreads();
#pragma unroll
  for (int ss = 0; ss < 2; ++ss) {
    int s = t + ss * 256;
    int qs2 = s >> 8, n2 = (s >> 6) & 3, lane2 = s & 63;
    int g2 = lane2 >> 4, li2 = lane2 & 15;
    int base = (qs2 * 4 + n2) * 256 + lane2 * 4;
    f32x4 v0 = *(const f32x4*)&Pp[base];
    f32x4 v1 = *(const f32x4*)&Pp[base + 2048];
    f32x4 v2 = *(const f32x4*)&Pp[base + 4096];
    f32x4 v3 = *(const f32x4*)&Pp[base + 6144];
    int col = n2 * 16 + li2;
    float wc = Wt[(size_t)col * 385 + 384], bb = bt[col];
#pragma unroll
    for (int r = 0; r < 4; ++r) {
      int row = qs2 * 16 + g2 * 4 + r;
      float val = v0[r] + v1[r] + v2[r] + v3[r] + bb + bil[i0 + row] * wc;
      Hl[row][col] = f2bf(val);
    }
  }
  __syncthreads();
  {
    int row = t >> 3, seg = t & 7;
    *(uint4*)&hb[(size_t)(i0 + row) * 64 + seg * 8] = *(uint4*)&Hl[row][seg * 8];
  }
  // ---- phase B: q/k/v (wave w owns output cols w*16..+15), fp8 emission ----
  short8 ha[2][2];
#pragma unroll
  for (int qs = 0; qs < 2; ++qs)
#pragma unroll
    for (int ks = 0; ks < 2; ++ks)
      ha[qs][ks] = *(const short8*)&Hl[qs * 16 + li][ks * 32 + g * 8];
  const float* Wm[3] = {Wsaq, Wsak, Wsav};
  f32x4 pacc[3][2];
#pragma unroll
  for (int m = 0; m < 3; ++m)
#pragma unroll
    for (int qs = 0; qs < 2; ++qs) pacc[m][qs] = (f32x4){0.f, 0.f, 0.f, 0.f};
#pragma unroll
  for (int m = 0; m < 3; ++m)
#pragma unroll
    for (int ks = 0; ks < 2; ++ks) {
      const float* wp = Wm[m] + (size_t)(w * 16 + li) * 64 + ks * 32 + g * 8;
      float4 b0 = *(const float4*)wp;
      float4 b1 = *(const float4*)(wp + 4);
      short8 bf;
      bf[0] = f2bf(b0.x); bf[1] = f2bf(b0.y); bf[2] = f2bf(b0.z); bf[3] = f2bf(b0.w);
      bf[4] = f2bf(b1.x); bf[5] = f2bf(b1.y); bf[6] = f2bf(b1.z); bf[7] = f2bf(b1.w);
      pacc[m][0] = __builtin_amdgcn_mfma_f32_16x16x32_bf16(ha[0][ks], bf, pacc[m][0], 0, 0, 0);
      pacc[m][1] = __builtin_amdgcn_mfma_f32_16x16x32_bf16(ha[1][ks], bf, pacc[m][1], 0, 0, 0);
    }
  const int col = w * 16 + li;
  const float QSC = 0.18033688011112042f;  // log2(e)/8
  {
    float bbq = bq[col], bbk = bk2[col], bbv = bv[col];
#pragma unroll
    for (int qs = 0; qs < 2; ++qs) {
      unsigned uq = pk8((pacc[0][qs][0] + bbq) * QSC, (pacc[0][qs][1] + bbq) * QSC,
                        (pacc[0][qs][2] + bbq) * QSC, (pacc[0][qs][3] + bbq) * QSC);
      unsigned uk = pk8(pacc[1][qs][0] + bbk, pacc[1][qs][1] + bbk,
                        pacc[1][qs][2] + bbk, pacc[1][qs][3] + bbk);
      unsigned uv = pk8(pacc[2][qs][0] + bbv, pacc[2][qs][1] + bbv,
                        pacc[2][qs][2] + bbv, pacc[2][qs][3] + bbv);
#pragma unroll
      for (int r = 0; r < 4; ++r) {
        Q8[qs * 16 + g * 4 + r][col] = (unsigned char)(uq >> (8 * r));
        K8[qs * 16 + g * 4 + r][col] = (unsigned char)(uk >> (8 * r));
      }
      *(unsigned*)&V8s[col][qs * 16 + g * 4] = uv;
    }
  }
  __syncthreads();
  // emission: q/k row-major frags, v col-major frags
  {
    const int h = t & 1, l2 = (t >> 1) & 63, loc = t >> 7;
    const int srow = (l2 & 15) + 16 * loc;
    const int scol = h * 32 + (l2 >> 4) * 8;
    unsigned long vq = *(const unsigned long*)&Q8[srow][scol];
    *(unsigned long*)(qb8 + ((size_t)((i0 >> 4) + loc) * 1024 + l2 * 16 + h * 8)) = vq;
    unsigned long vk = *(const unsigned long*)&K8[srow][scol];
    *(unsigned long*)(kb8 + ((size_t)((i0 >> 6) * 4 + ((i0 >> 4) & 3) + loc) * 1024 + l2 * 16 + h * 8)) = vk;
    const int dt = t >> 6, l3 = t & 63;
    unsigned long vv = *(const unsigned long*)&V8s[dt * 16 + (l3 & 15)][(l3 >> 4) * 8];
    *(unsigned long*)(vl8 + ((size_t)((i0 >> 6) * 4 + dt) * 1024 + l3 * 16 + ((i0 >> 5) & 1) * 8)) = vv;
  }
}

// ---------------- K2: fp8 LDS-staged attention, swapped QK^T, 8-way key split ----------------
// Single change vs R8: PV phase hoists P fragments and shares each V fragment read across qs.
__global__ __launch_bounds__(128, 2) void ca_attn7(
    const uint4* __restrict__ qb8, const unsigned* __restrict__ kb8,
    const unsigned* __restrict__ vl8,
    unsigned* __restrict__ pOu, float* __restrict__ pL, int N) {
  __shared__ unsigned Kl[2][1024];
  __shared__ unsigned Vl[2][1024];
  __shared__ unsigned Pl[2][2][256];
  const int t = threadIdx.x, lane = t & 63, wid = t >> 6;
  const int g = lane >> 4, li = lane & 15;
  const int bid = blockIdx.x;
  const int sp = bid & 7, qblk = bid >> 3;
  const int i0 = qblk * 64 + wid * 32;
  const int ntil = N >> 9;
  const int tile0 = sp * ntil;

#define STG(b, T)                                                                                  \
  do {                                                                                             \
    gload16(kb8 + (((size_t)(T) * 4 + 2 * wid) << 8) + lane * 4,     &Kl[b][(2 * wid) * 256]);     \
    gload16(kb8 + (((size_t)(T) * 4 + 2 * wid + 1) << 8) + lane * 4, &Kl[b][(2 * wid + 1) * 256]); \
    gload16(vl8 + (((size_t)(T) * 4 + 2 * wid) << 8) + lane * 4,     &Vl[b][(2 * wid) * 256]);     \
    gload16(vl8 + (((size_t)(T) * 4 + 2 * wid + 1) << 8) + lane * 4, &Vl[b][(2 * wid + 1) * 256]); \
  } while (0)

  long2t qf[2];
  qf[0] = as_l2(qb8[(size_t)((i0 >> 4) + 0) * 64 + lane]);
  qf[1] = as_l2(qb8[(size_t)((i0 >> 4) + 1) * 64 + lane]);

  f32x4 acc[2][4];
  float rs[2] = {0.f, 0.f};
#pragma unroll
  for (int qs = 0; qs < 2; ++qs)
#pragma unroll
    for (int n = 0; n < 4; ++n) acc[qs][n] = (f32x4){0.f, 0.f, 0.f, 0.f};

  STG(0, tile0);
  asm volatile("s_waitcnt vmcnt(0)" ::: "memory");

  for (int tt = 0; tt < ntil; ++tt) {
    const int cur = tt & 1;
    __builtin_amdgcn_s_barrier();
    if (tt + 1 < ntil) STG(cur ^ 1, tile0 + tt + 1);

    f32x4 s4[2][4];
#pragma unroll
    for (int qs = 0; qs < 2; ++qs)
#pragma unroll
      for (int t4 = 0; t4 < 4; ++t4) s4[qs][t4] = (f32x4){0.f, 0.f, 0.f, 0.f};
    __builtin_amdgcn_s_setprio(1);
#pragma unroll
    for (int t4 = 0; t4 < 4; ++t4) {
      long2t kl = as_l2(*(const uint4*)&Kl[cur][t4 * 256 + lane * 4]);
      s4[0][t4] = __builtin_amdgcn_mfma_f32_16x16x32_fp8_fp8(kl.x, qf[0].x, s4[0][t4], 0, 0, 0);
      s4[0][t4] = __builtin_amdgcn_mfma_f32_16x16x32_fp8_fp8(kl.y, qf[0].y, s4[0][t4], 0, 0, 0);
      s4[1][t4] = __builtin_amdgcn_mfma_f32_16x16x32_fp8_fp8(kl.x, qf[1].x, s4[1][t4], 0, 0, 0);
      s4[1][t4] = __builtin_amdgcn_mfma_f32_16x16x32_fp8_fp8(kl.y, qf[1].y, s4[1][t4], 0, 0, 0);
    }
    __builtin_amdgcn_s_setprio(0);
#pragma unroll
    for (int qs = 0; qs < 2; ++qs) {
#pragma unroll
      for (int t4 = 0; t4 < 4; ++t4) {
        float p0, p1, p2, p3;
        asm("v_exp_f32 %0, %1" : "=v"(p0) : "v"(s4[qs][t4][0]));
        asm("v_exp_f32 %0, %1" : "=v"(p1) : "v"(s4[qs][t4][1]));
        asm("v_exp_f32 %0, %1" : "=v"(p2) : "v"(s4[qs][t4][2]));
        asm("v_exp_f32 %0, %1" : "=v"(p3) : "v"(s4[qs][t4][3]));
        rs[qs] += (p0 + p1) + (p2 + p3);
        unsigned u = pk8(p0, p1, p2, p3);
        Pl[wid][qs][(li + 16 * ((t4 & 1) * 2 + (g >> 1))) * 4 + (t4 >> 1) * 2 + (g & 1)] = u;
      }
    }
    asm volatile("s_waitcnt lgkmcnt(0)" ::: "memory");
    long2t pf0 = as_l2(*(const uint4*)&Pl[wid][0][lane * 4]);
    long2t pf1 = as_l2(*(const uint4*)&Pl[wid][1][lane * 4]);
    __builtin_amdgcn_s_setprio(1);
#pragma unroll
    for (int dt = 0; dt < 4; ++dt) {
      long2t vf = as_l2(*(const uint4*)&Vl[cur][dt * 256 + lane * 4]);
      acc[0][dt] = __builtin_amdgcn_mfma_f32_16x16x32_fp8_fp8(pf0.x, vf.x, acc[0][dt], 0, 0, 0);
      acc[0][dt] = __builtin_amdgcn_mfma_f32_16x16x32_fp8_fp8(pf0.y, vf.y, acc[0][dt], 0, 0, 0);
      acc[1][dt] = __builtin_amdgcn_mfma_f32_16x16x32_fp8_fp8(pf1.x, vf.x, acc[1][dt], 0, 0, 0);
      acc[1][dt] = __builtin_amdgcn_mfma_f32_16x16x32_fp8_fp8(pf1.y, vf.y, acc[1][dt], 0, 0, 0);
    }
    __builtin_amdgcn_s_setprio(0);
    asm volatile("s_waitcnt vmcnt(0)" ::: "memory");
  }
#undef STG

  const size_t ob = ((size_t)sp * (N >> 5) + (i0 >> 5)) * 2;
#pragma unroll
  for (int qs = 0; qs < 2; ++qs) {
#pragma unroll
    for (int dt = 0; dt < 4; ++dt) {
      uint2 wv;
      wv.x = cvtpk(acc[qs][dt][0], acc[qs][dt][1]);
      wv.y = cvtpk(acc[qs][dt][2], acc[qs][dt][3]);
      *(uint2*)&pOu[((ob + qs) * 4 + dt) * 128 + lane * 2] = wv;
    }
    float r2 = rs[qs] + __shfl_xor(rs[qs], 16, 64);
    r2 += __shfl_xor(r2, 32, 64);
    if (lane < 16) pL[(size_t)sp * N + i0 + qs * 16 + lane] = r2;
  }
}

// ---------------- K3: merge 8 splits (fragment layout) + residual + cross-attn + epilogue ------
__global__ __launch_bounds__(256) void ca_merge3(
    const short* __restrict__ hb, const unsigned* __restrict__ pOu, const float* __restrict__ pL,
    const float* __restrict__ u_ws, const float* __restrict__ scal,
    const float* __restrict__ bil, const float* __restrict__ Wsc,
    const float* __restrict__ bsc_p, const float* __restrict__ rgate_p,
    float* __restrict__ out, int N) {
  const int t = threadIdx.x;
  const int rp = t >> 3, e = t & 7;
  const int dt2 = e >> 1, li0 = (e & 1) * 8;
  const float gate = 1.f / (1.f + __expf(-rgate_p[0]));
  const float bsc = bsc_p[0], sc0 = scal[0], sc1 = scal[1];
  const int R0 = blockIdx.x * 64 + rp * 2;
  const int b32 = R0 >> 5, qs2 = (R0 >> 4) & 1, g2 = (R0 >> 2) & 3;
  const int rpair = (R0 & 3) >> 1;
  float o0[8], o1[8], L0 = 0.f, L1 = 0.f;
#pragma unroll
  for (int j = 0; j < 8; ++j) { o0[j] = 0.f; o1[j] = 0.f; }
#pragma unroll
  for (int sp2 = 0; sp2 < 8; ++sp2) {
    size_t base = ((((size_t)sp2 * (N >> 5) + b32) * 2 + qs2) * 4 + dt2) * 128
                  + (g2 * 16 + li0) * 2 + rpair;
#pragma unroll
    for (int j = 0; j < 8; ++j) {
      unsigned u = pOu[base + 2 * j];
      o0[j] += bf2f((short)(u & 0xffff));
      o1[j] += bf2f((short)(u >> 16));
    }
    L0 += pL[(size_t)sp2 * N + R0];
    L1 += pL[(size_t)sp2 * N + R0 + 1];
  }
  const float iL0 = 1.f / L0, iL1 = 1.f / L1;
  const int c0 = dt2 * 16 + li0;
  short8 hv0 = *(const short8*)&hb[(size_t)R0 * 64 + c0];
  short8 hv1 = *(const short8*)&hb[(size_t)(R0 + 1) * 64 + c0];
  float s1a = 0.f, s2a = 0.f, s1b = 0.f, s2b = 0.f;
#pragma unroll
  for (int j = 0; j < 8; ++j) {
    float uwsj = u_ws[c0 + j], wscj = Wsc[c0 + j];
    float h0 = bf2f(hv0[j]) + o0[j] * iL0;
    float h1 = bf2f(hv1[j]) + o1[j] * iL1;
    s1a += h0 * uwsj; s2a += h0 * wscj;
    s1b += h1 * uwsj; s2b += h1 * wscj;
  }
#pragma unroll
  for (int mask = 1; mask < 8; mask <<= 1) {
    s1a += __shfl_xor(s1a, mask, 64);
    s2a += __shfl_xor(s2a, mask, 64);
    s1b += __shfl_xor(s1b, mask, 64);
    s2b += __shfl_xor(s2b, mask, 64);
  }
  if (e == 0) {
    float cawa = 1.f / (1.f + __expf(-(s1a + sc0) * 0.125f));
    float cawb = 1.f / (1.f + __expf(-(s1b + sc0) * 0.125f));
    float scoreA = s2a + cawa * sc1 + bsc;
    float scoreB = s2b + cawb * sc1 + bsc;
    out[R0] = (1.f - gate) * bil[R0] + gate * scoreA;
    out[R0 + 1] = (1.f - gate) * bil[R0 + 1] + gate * scoreB;
  }
}

extern "C" void kernel_launch(void* const* d_in, const int* in_sizes, int n_in,
                              void* d_out, int out_size, void* d_ws, size_t ws_size,
                              hipStream_t stream) {
  const float* sit  = (const float*)d_in[0];
  const float* te   = (const float*)d_in[1];
  const float* bil  = (const float*)d_in[2];
  const float* Wt   = (const float*)d_in[3];
  const float* bt   = (const float*)d_in[4];
  const float* Ws   = (const float*)d_in[5];
  const float* bs   = (const float*)d_in[6];
  const float* Wsaq = (const float*)d_in[7];
  const float* bsaq = (const float*)d_in[8];
  const float* Wsak = (const float*)d_in[9];
  const float* bsak = (const float*)d_in[10];
  const float* Wsav = (const float*)d_in[11];
  const float* bsav = (const float*)d_in[12];
  const float* Wcq  = (const float*)d_in[13];
  const float* bcq  = (const float*)d_in[14];
  const float* Wck  = (const float*)d_in[15];
  const float* bck  = (const float*)d_in[16];
  const float* Wcv  = (const float*)d_in[17];
  const float* bcv  = (const float*)d_in[18];
  const float* Wsc  = (const float*)d_in[19];
  const float* bsc  = (const float*)d_in[20];
  const float* rgate= (const float*)d_in[21];
  const int N = in_sizes[2];

  char* w = (char*)d_ws;
  size_t off = 0;
  short* hbuf        = (short*)(w + off);         off += (size_t)N * 64 * 2;
  unsigned char* qb8 = (unsigned char*)(w + off); off += (size_t)N * 64;
  unsigned char* kb8 = (unsigned char*)(w + off); off += (size_t)N * 64;
  unsigned char* vl8 = (unsigned char*)(w + off); off += (size_t)N * 64;
  float* u_ws        = (float*)(w + off);         off += 64 * 4;
  float* scal        = (float*)(w + off);         off += 4 * 4;
  unsigned* pOu      = (unsigned*)(w + off);      off += (size_t)8 * N * 64 * 2;
  float* pL          = (float*)(w + off);         off += (size_t)8 * N * 4;

  ca_proj4<<<N / 32 + 1, 256, 0, stream>>>(te, bil, Wt, bt, Wsaq, bsaq, Wsak, bsak,
                                           Wsav, bsav, hbuf, qb8, kb8, vl8,
                                           sit, Ws, bs, Wck, bck, Wcv, bcv, Wcq, bcq, Wsc,
                                           u_ws, scal, N);
  ca_attn7<<<N / 8, 128, 0, stream>>>((const uint4*)qb8, (const unsigned*)kb8,
                                      (const unsigned*)vl8, pOu, pL, N);
  ca_merge3<<<N / 64, 256, 0, stream>>>(hbuf, pOu, pL, u_ws, scal, bil, Wsc, bsc, rgate,
                                        (float*)d_out, N);
}